// Round 5
// baseline (1049.819 us; speedup 1.0000x reference)
//
#include <hip/hip_runtime.h>
#include <math.h>

#define D 64
#define RELS 8

__device__ __forceinline__ float lrelu(float e){ return e > 0.f ? e : 0.2f*e; }

// ---- knode: per-block compute v (W_r@a_src, W_r@a_dst) in LDS, then per-node
// logits s,d for all relations (layout [rel*N + n])
__global__ void knode(const float* __restrict__ x, const float* __restrict__ W,
                      const float* __restrict__ a_src, const float* __restrict__ a_dst,
                      float* __restrict__ s_all, float* __restrict__ d_all, int N){
  __shared__ float vs[2*RELS*D];
  int t = threadIdx.x;
  // 1024 entries: e = dir*512 + r*64 + col
  #pragma unroll
  for (int i = 0; i < 4; ++i){
    int e = t + i*256;
    int dir = e >> 9, r = (e >> 6) & 7, col = e & 63;
    const float* Wrow = W + (size_t)r*D*D + (size_t)col*D;
    const float* av = (dir ? a_dst : a_src) + r*D;
    float acc = 0.f;
    for (int f = 0; f < D; f += 4){
      float4 wv = *(const float4*)(Wrow + f);
      float4 aa = *(const float4*)(av + f);
      acc += wv.x*aa.x + wv.y*aa.y + wv.z*aa.z + wv.w*aa.w;
    }
    vs[e] = acc;
  }
  __syncthreads();
  int n = blockIdx.x*blockDim.x + t;
  if (n >= N) return;
  float s[RELS], dd[RELS];
  #pragma unroll
  for (int r = 0; r < RELS; ++r){ s[r] = 0.f; dd[r] = 0.f; }
  const float* xr = x + (size_t)n*D;
  for (int k = 0; k < D; k += 4){
    float4 xv = *(const float4*)(xr + k);
    #pragma unroll
    for (int r = 0; r < RELS; ++r){
      s[r]  += xv.x*vs[r*D+k]   + xv.y*vs[r*D+k+1]   + xv.z*vs[r*D+k+2]   + xv.w*vs[r*D+k+3];
      dd[r] += xv.x*vs[512+r*D+k] + xv.y*vs[512+r*D+k+1]
             + xv.z*vs[512+r*D+k+2] + xv.w*vs[512+r*D+k+3];
    }
  }
  #pragma unroll
  for (int r = 0; r < RELS; ++r){
    s_all[(size_t)r*N + n] = s[r];
    d_all[(size_t)r*N + n] = dd[r];
  }
}

// ---- khist: count edges per key = rel*N + dst
__global__ void khist(const int* __restrict__ dst, const int* __restrict__ et,
                      int* __restrict__ hist, int E, int N){
  int stride = gridDim.x*blockDim.x;
  for (int i = blockIdx.x*blockDim.x+threadIdx.x; i < E; i += stride)
    atomicAdd(&hist[(size_t)et[i]*N + dst[i]], 1);
}

// ---- 3-kernel exclusive scan of hist[0..NK) into off[0..NK], off[0]=0; cur=off copy
__global__ void kscan1(const int* __restrict__ hist, int* __restrict__ off,
                       int* __restrict__ bsums, int NK){
  __shared__ int tot[256];
  int b = blockIdx.x, t = threadIdx.x;
  int base = b*2048 + t*8;
  int v[8]; int c = 0;
  #pragma unroll
  for (int j = 0; j < 8; ++j){ int idx = base+j; int h = (idx<NK)? hist[idx]:0; c += h; v[j] = c; }
  tot[t] = c; __syncthreads();
  for (int o = 1; o < 256; o <<= 1){
    int add = (t >= o) ? tot[t-o] : 0;
    __syncthreads();
    tot[t] += add;
    __syncthreads();
  }
  int excl = (t == 0) ? 0 : tot[t-1];
  if (t == 255) bsums[b] = tot[255];
  #pragma unroll
  for (int j = 0; j < 8; ++j){ int idx = base+j; if (idx < NK) off[idx+1] = v[j] + excl; }
}

__global__ void kscan2(int* __restrict__ bsums, int NB){
  __shared__ int s[512];
  int t = threadIdx.x;
  s[t] = (t < NB) ? bsums[t] : 0;
  __syncthreads();
  for (int o = 1; o < 512; o <<= 1){
    int add = (t >= o) ? s[t-o] : 0;
    __syncthreads();
    s[t] += add;
    __syncthreads();
  }
  if (t < NB) bsums[t] = (t == 0) ? 0 : s[t-1];
}

__global__ void kscan3(int* __restrict__ off, int* __restrict__ cur,
                       const int* __restrict__ bsums, int NK){
  int b = blockIdx.x, t = threadIdx.x;
  int add = bsums[b];
  int base = b*2048 + t*8;
  #pragma unroll
  for (int j = 0; j < 8; ++j){
    int id1 = base+j+1;
    if (id1 <= NK){
      int nv = off[id1] + add;
      off[id1] = nv;
      if (id1 < NK) cur[id1] = nv;
    }
  }
  if (b == 0 && t == 0){ off[0] = 0; cur[0] = 0; }
}

// ---- kscatter: counting-sort placement; store (src,dst) record + raw logit
__global__ void kscatter(const int* __restrict__ src, const int* __restrict__ dst,
                         const int* __restrict__ et, const float* __restrict__ s_all,
                         const float* __restrict__ d_all, int* __restrict__ cur,
                         int2* __restrict__ edge2, float* __restrict__ se, int E, int N){
  int stride = gridDim.x*blockDim.x;
  for (int i = blockIdx.x*blockDim.x+threadIdx.x; i < E; i += stride){
    int r = et[i], dn = dst[i], sn = src[i];
    int pos = atomicAdd(&cur[(size_t)r*N + dn], 1);
    edge2[pos] = make_int2(sn, dn);
    se[pos] = lrelu(s_all[(size_t)r*N + sn] + d_all[(size_t)r*N + dn]);
  }
}

// ---- kseg: per-(rel,node) segment softmax, streaming (se: logits -> alpha), + aself
__global__ void kseg(const float* __restrict__ s_all, const float* __restrict__ d_all,
                     const int* __restrict__ off, float* __restrict__ se,
                     float* __restrict__ aself, int NK){
  int stride = gridDim.x*blockDim.x;
  for (int k = blockIdx.x*blockDim.x+threadIdx.x; k < NK; k += stride){
    int s0 = off[k], s1 = off[k+1];
    float eself = lrelu(s_all[k] + d_all[k]);
    float m = eself;
    for (int i = s0; i < s1; ++i) m = fmaxf(m, se[i]);
    float den = __expf(eself - m);
    for (int i = s0; i < s1; ++i){
      float w = __expf(se[i] - m);
      se[i] = w;
      den += w;
    }
    float inv = 1.0f / den;
    for (int i = s0; i < s1; ++i) se[i] *= inv;
    aself[k] = __expf(eself - m) * inv;
  }
}

// ---- kmega: per 64-row tile: per relation, batched edge-parallel weighted gather
// into LDS (8-deep pipelined), then float4 GEMM-accumulate; rel==RELS is self-linear.
__global__ __launch_bounds__(256, 4) void kmega(const float* __restrict__ x,
    const float* __restrict__ W, const float* __restrict__ W_self,
    const float* __restrict__ b_self, const float* __restrict__ bias,
    const float* __restrict__ aself, const int* __restrict__ off,
    const int2* __restrict__ edge2, const float* __restrict__ se,
    float* __restrict__ out, int N){
  __shared__ float ag[64*68];
  __shared__ float wsh[64*64];
  int t = threadIdx.x;
  int row0 = blockIdx.x * 64;
  int nrow = min(64, N - row0);
  int wid = t >> 6, lane = t & 63;
  int sub = lane >> 4;          // 4 subgroups of 16 lanes, one edge each
  int l4 = (lane & 15) * 4;     // float4 column within row
  int tcol = (t & 15)*4, trow = (t >> 4)*4;
  float acc[4][4] = {};

  for (int rel = 0; rel <= RELS; ++rel){
    __syncthreads();   // previous GEMM done reading ag/wsh
    const float* Wm = (rel == RELS) ? W_self : (W + (size_t)rel*D*D);
    #pragma unroll
    for (int i = 0; i < 4; ++i){
      int o = (t + i*256)*4;
      *(float4*)(&wsh[o]) = *(const float4*)(Wm + o);
    }
    // init rows with self contribution
    for (int rl = wid; rl < nrow; rl += 4){
      int n = row0 + rl;
      float a = (rel == RELS) ? 1.0f : aself[(size_t)rel*N + n];
      ag[rl*68 + lane] = a * x[(size_t)n*D + lane];
    }
    __syncthreads();
    if (rel < RELS){
      int key0 = rel*N + row0;
      int e0 = off[key0], e1 = off[key0 + nrow];
      int len = e1 - e0;
      int q = len >> 2, rm = len & 3;
      int b0 = e0 + wid*q + min(wid, rm);
      int b1 = b0 + q + (wid < rm ? 1 : 0);
      int b1m = b1 - 1;
      for (int i0 = b0 + sub; i0 < b1; i0 += 32){
        int sn[8]; int rl[8]; float al[8];
        #pragma unroll
        for (int j = 0; j < 8; ++j){
          int i = min(i0 + 4*j, b1m);
          int2 e2 = edge2[i];
          sn[j] = e2.x; rl[j] = e2.y - row0;
          al[j] = se[i];
        }
        float4 xv[8];
        #pragma unroll
        for (int j = 0; j < 8; ++j)
          xv[j] = *(const float4*)(x + (size_t)sn[j]*D + l4);
        #pragma unroll
        for (int j = 0; j < 8; ++j){
          if (i0 + 4*j <= b1m){
            float* agp = &ag[rl[j]*68 + l4];
            atomicAdd(agp+0, al[j]*xv[j].x);
            atomicAdd(agp+1, al[j]*xv[j].y);
            atomicAdd(agp+2, al[j]*xv[j].z);
            atomicAdd(agp+3, al[j]*xv[j].w);
          }
        }
      }
      __syncthreads();
    }
    // GEMM accumulate: acc += ag @ wsh  (float4 LDS reads both sides)
    #pragma unroll 4
    for (int k4 = 0; k4 < 16; ++k4){
      int k = k4 << 2;
      float4 w0 = *(const float4*)(&wsh[(k+0)*64 + tcol]);
      float4 w1 = *(const float4*)(&wsh[(k+1)*64 + tcol]);
      float4 w2 = *(const float4*)(&wsh[(k+2)*64 + tcol]);
      float4 w3 = *(const float4*)(&wsh[(k+3)*64 + tcol]);
      #pragma unroll
      for (int j = 0; j < 4; ++j){
        float4 av = *(const float4*)(&ag[(trow+j)*68 + k]);
        acc[j][0] += av.x*w0.x + av.y*w1.x + av.z*w2.x + av.w*w3.x;
        acc[j][1] += av.x*w0.y + av.y*w1.y + av.z*w2.y + av.w*w3.y;
        acc[j][2] += av.x*w0.z + av.y*w1.z + av.z*w2.z + av.w*w3.z;
        acc[j][3] += av.x*w0.w + av.y*w1.w + av.z*w2.w + av.w*w3.w;
      }
    }
  }

  // bias: bsum = b_self + sum_r bias[r]
  float4 bb = *(const float4*)(b_self + tcol);
  #pragma unroll
  for (int r = 0; r < RELS; ++r){
    float4 bv = *(const float4*)(bias + r*D + tcol);
    bb.x += bv.x; bb.y += bv.y; bb.z += bv.z; bb.w += bv.w;
  }
  #pragma unroll
  for (int j = 0; j < 4; ++j){
    int n = row0 + trow + j;
    if (n < N){
      float4 o = make_float4(acc[j][0]+bb.x, acc[j][1]+bb.y, acc[j][2]+bb.z, acc[j][3]+bb.w);
      *(float4*)(out + (size_t)n*D + tcol) = o;
    }
  }
}

extern "C" void kernel_launch(void* const* d_in, const int* in_sizes, int n_in,
                              void* d_out, int out_size, void* d_ws, size_t ws_size,
                              hipStream_t stream) {
  const float* x      = (const float*)d_in[0];
  const int*   ei     = (const int*)d_in[1];
  const int*   et     = (const int*)d_in[2];
  const float* W_self = (const float*)d_in[3];
  const float* b_self = (const float*)d_in[4];
  const float* W      = (const float*)d_in[5];
  const float* a_src  = (const float*)d_in[6];
  const float* a_dst  = (const float*)d_in[7];
  const float* bias   = (const float*)d_in[8];

  int N = in_sizes[0] / D;
  int E = in_sizes[2];
  int NK = N * RELS;
  float* out = (float*)d_out;

  float* ws    = (float*)d_ws;
  float* s_all = ws;                         // NK
  float* d_all = s_all + (size_t)NK;         // NK
  float* aself = d_all + (size_t)NK;         // NK
  int* hist    = (int*)(aself + (size_t)NK); // NK
  int* off     = hist + (size_t)NK;          // NK+16
  int* cur     = off + (size_t)NK + 16;      // NK
  int* bsums   = cur + (size_t)NK;           // 512
  int2* edge2  = (int2*)(bsums + 512);       // E (8B records)
  float* se    = (float*)(edge2 + (size_t)E);// E

  const int* srcp = ei;
  const int* dstp = ei + E;

  knode<<<(N + 255)/256, 256, 0, stream>>>(x, W, a_src, a_dst, s_all, d_all, N);

  hipMemsetAsync(hist, 0, (size_t)NK*sizeof(int), stream);
  khist<<<2048, 256, 0, stream>>>(dstp, et, hist, E, N);

  int NB = (NK + 2047) / 2048;
  kscan1<<<NB, 256, 0, stream>>>(hist, off, bsums, NK);
  kscan2<<<1, 512, 0, stream>>>(bsums, NB);
  kscan3<<<NB, 256, 0, stream>>>(off, cur, bsums, NK);

  kscatter<<<2048, 256, 0, stream>>>(srcp, dstp, et, s_all, d_all, cur, edge2, se, E, N);
  kseg<<<1024, 256, 0, stream>>>(s_all, d_all, off, se, aself, NK);

  kmega<<<(N + 63)/64, 256, 0, stream>>>(x, W, W_self, b_self, bias, aself,
                                         off, edge2, se, out, N);
}